// Round 20
// baseline (189.466 us; speedup 1.0000x reference)
//
#include <hip/hip_runtime.h>

#define N_NODES 100000
#define N_EDGES 1000000
#define EPS 1e-5f
#define SLOPE 0.01f
#define NBUCK 391    // ceil(N/256) buckets of 256 consecutive nodes
#define EPB 2560     // edges per bin block
#define NBINB 391    // bin blocks
#define KSUB 8       // sub-cursors per bucket (blockIdx % 8)
#define SCAP 480     // records per (bucket, sub): mean 320 + 8.9 sigma
#define CCAP 3072    // compacted records per bucket in gather LDS

// ---------------------------------------------------------------------------
// ws layout:
//   pef  : NBUCK*KSUB*SCAP*16 B (24.0 MB) edge features, (bucket, sub)-major
//   meta : NBUCK*KSUB*SCAP*4 B  (6.0 MB)  (src<<8 | dst&255) per record
//   bcur : NBUCK*KSUB ints [zeroed]       sub-cursors
//   stats: 32 floats [zeroed]             sum[16], sumsq[16]
// Measured design rules:
//   r5/r6/r16: 1 thread/node is the right gather shape (all lane-splits lose).
//   r8/r9 : grid.sync fusion is NOT coherence-safe on 8-XCD MI355X.
//   r10   : nt stores/L2-bypass regress; plain cached stores optimal.
//   r12-15: same-address atomic RMW = 137 ns; 8-way sub-cursors @391 blocks.
//   r17-19: 20 B/edge bin format + ef staged in LDS (grid-limited -> LDS
//           free): gather FETCH at floor (41.5 MB), 0.8 TB/s, occ 14%
//           (1.5 waves/SIMD, pinned by N_NODES) -> latency-bound.
//   r20   : phase D unroll x4 -> x8 (8 v-lines + 8 ef in flight per chunk).
//           VGPR rise is free (grid-limited). r7 precedent: ILP pays when
//           latency-bound; r3 precedent: useless only at fetch ceiling.
// ---------------------------------------------------------------------------

// Kernel 1: bin edges into (bucket, sub)-major staging. (r17-r19, unchanged)
__global__ __launch_bounds__(256) void bin_kernel(
    const float* __restrict__ efeat,
    const int* __restrict__ edge_index,
    int* __restrict__ bcur,
    float4* __restrict__ pef,
    unsigned int* __restrict__ meta)
{
    __shared__ int s_hist[NBUCK];
    __shared__ int s_base[NBUCK];

    const int tid = threadIdx.x;
    const int ksub = blockIdx.x & (KSUB - 1);
    const int e0 = blockIdx.x * EPB;
    const int e1 = min(e0 + EPB, N_EDGES);

    for (int i = tid; i < NBUCK; i += 256) s_hist[i] = 0;
    __syncthreads();
    for (int eid = e0 + tid; eid < e1; eid += 256) {
        int dst = edge_index[N_EDGES + eid];
        atomicAdd(&s_hist[dst >> 8], 1);
    }
    __syncthreads();

    for (int b = tid; b < NBUCK; b += 256) {
        int c = s_hist[b];
        s_base[b] = c ? atomicAdd(bcur + b * KSUB + ksub, c) : 0;
    }
    __syncthreads();
    for (int i = tid; i < NBUCK; i += 256) s_hist[i] = 0;   // reuse as cursor
    __syncthreads();

    for (int eid = e0 + tid; eid < e1; eid += 256) {
        int src = edge_index[eid];
        int dst = edge_index[N_EDGES + eid];
        float4 ef = *(const float4*)(efeat + (size_t)eid * 4);
        int b = dst >> 8;
        int slot = s_base[b] + atomicAdd(&s_hist[b], 1);
        if (slot < SCAP) {                      // 8.9-sigma margin; never trips
            size_t rec = ((size_t)b * KSUB + ksub) * SCAP + slot;
            pef[rec]  = ef;
            meta[rec] = ((unsigned)src << 8) | (unsigned)(dst & 255);
        }
    }
}

// per-edge FMA accumulate into acc[80]
#define EDGE_FMA(EF, A0, A1, A2, A3)                                        \
    {                                                                       \
        acc[ 0] += (A0).x; acc[ 1] += (A0).y;                               \
        acc[ 2] += (A0).z; acc[ 3] += (A0).w;                               \
        acc[ 4] += (A1).x; acc[ 5] += (A1).y;                               \
        acc[ 6] += (A1).z; acc[ 7] += (A1).w;                               \
        acc[ 8] += (A2).x; acc[ 9] += (A2).y;                               \
        acc[10] += (A2).z; acc[11] += (A2).w;                               \
        acc[12] += (A3).x; acc[13] += (A3).y;                               \
        acc[14] += (A3).z; acc[15] += (A3).w;                               \
        const float4 av_[4] = {A0, A1, A2, A3};                             \
        _Pragma("unroll")                                                   \
        for (int i_ = 0; i_ < 4; ++i_) {                                    \
            float4 a_ = av_[i_];                                            \
            acc[16 + i_*4+0] = fmaf((EF).x, a_.x, acc[16 + i_*4+0]);        \
            acc[16 + i_*4+1] = fmaf((EF).x, a_.y, acc[16 + i_*4+1]);        \
            acc[16 + i_*4+2] = fmaf((EF).x, a_.z, acc[16 + i_*4+2]);        \
            acc[16 + i_*4+3] = fmaf((EF).x, a_.w, acc[16 + i_*4+3]);        \
            acc[32 + i_*4+0] = fmaf((EF).y, a_.x, acc[32 + i_*4+0]);        \
            acc[32 + i_*4+1] = fmaf((EF).y, a_.y, acc[32 + i_*4+1]);        \
            acc[32 + i_*4+2] = fmaf((EF).y, a_.z, acc[32 + i_*4+2]);        \
            acc[32 + i_*4+3] = fmaf((EF).y, a_.w, acc[32 + i_*4+3]);        \
            acc[48 + i_*4+0] = fmaf((EF).z, a_.x, acc[48 + i_*4+0]);        \
            acc[48 + i_*4+1] = fmaf((EF).z, a_.y, acc[48 + i_*4+1]);        \
            acc[48 + i_*4+2] = fmaf((EF).z, a_.z, acc[48 + i_*4+2]);        \
            acc[48 + i_*4+3] = fmaf((EF).z, a_.w, acc[48 + i_*4+3]);        \
            acc[64 + i_*4+0] = fmaf((EF).w, a_.x, acc[64 + i_*4+0]);        \
            acc[64 + i_*4+1] = fmaf((EF).w, a_.y, acc[64 + i_*4+1]);        \
            acc[64 + i_*4+2] = fmaf((EF).w, a_.z, acc[64 + i_*4+2]);        \
            acc[64 + i_*4+3] = fmaf((EF).w, a_.w, acc[64 + i_*4+3]);        \
        }                                                                   \
    }

// ---------------------------------------------------------------------------
// Kernel 2: per-bucket fused CSR-build + gather + node transform.
// Phase D: x8 unroll — one contiguous LDS round (8 metaS), then 8 v-lines +
// 8 LDS ef reads in flight. VGPR headroom is free (grid-limited occupancy).
// ---------------------------------------------------------------------------
__global__ __launch_bounds__(256) void gather_bucket_kernel(
    const float* __restrict__ v,
    const float4* __restrict__ pef,
    const unsigned int* __restrict__ meta,
    const int* __restrict__ bcur,
    const float* __restrict__ enet_w,
    const float* __restrict__ enet_b,
    const float* __restrict__ root,
    const float* __restrict__ bias,
    float* __restrict__ out,
    float* __restrict__ stats)
{
    __shared__ float4 s_efA[CCAP];            // 48 KB  ef, compact order
    __shared__ unsigned int s_metaA[CCAP];    // 12 KB  src*4096+pos, compact
    __shared__ unsigned char s_dl[CCAP];      // 3 KB   local dst, compact
    __shared__ unsigned int s_metaS[CCAP];    // 12 KB  src*4096+pos, CSR order
    __shared__ int s_hist[256];
    __shared__ int s_sc[256];
    __shared__ int s_cur[256];
    __shared__ float s_part[4][32];

    const int b = blockIdx.x;
    const int tid = threadIdx.x;

    // A) segment counts (uniform), stage ef + meta -> LDS, histogram
    int ck[KSUB], off[KSUB];
    int cnt = 0;
    #pragma unroll
    for (int k = 0; k < KSUB; ++k) {
        int c = min(bcur[b * KSUB + k], SCAP);
        if (cnt + c > CCAP) c = CCAP - cnt;
        off[k] = cnt;
        ck[k] = c;
        cnt += c;
    }
    s_hist[tid] = 0;
    __syncthreads();
    #pragma unroll
    for (int k = 0; k < KSUB; ++k) {
        size_t segbase = ((size_t)b * KSUB + k) * SCAP;
        for (int i = tid; i < ck[k]; i += 256) {
            unsigned m = meta[segbase + i];
            int pos = off[k] + i;
            int d = (int)(m & 255u);
            s_efA[pos] = pef[segbase + i];
            s_metaA[pos] = (m >> 8) * 4096u + (unsigned)pos;
            s_dl[pos] = (unsigned char)d;
            atomicAdd(&s_hist[d], 1);
        }
    }
    __syncthreads();

    // B) exclusive scan of s_hist
    int deg = s_hist[tid];
    s_sc[tid] = deg;
    __syncthreads();
    #pragma unroll
    for (int offs = 1; offs < 256; offs <<= 1) {
        int t = (tid >= offs) ? s_sc[tid - offs] : 0;
        __syncthreads();
        s_sc[tid] += t;
        __syncthreads();
    }
    int start = s_sc[tid] - deg;
    s_cur[tid] = start;
    __syncthreads();

    // C) scatter SORTED payload: s_metaS[csr_slot] = src*4096 + compact_pos
    for (int i = tid; i < cnt; i += 256) {
        int slot = atomicAdd(&s_cur[s_dl[i]], 1);
        s_metaS[slot] = s_metaA[i];
    }
    __syncthreads();

    // D) gather, x8 unroll: 8 contiguous LDS metaS reads -> 8 independent
    //    v-line globals + 8 LDS ef reads in flight per chunk.
    int n = b * 256 + tid;
    bool active = (n < N_NODES);

    float acc[80];
    #pragma unroll
    for (int i = 0; i < 80; ++i) acc[i] = 0.0f;

    int j = 0;
    for (; j + 8 <= deg; j += 8) {
        unsigned mm[8];
        #pragma unroll
        for (int u = 0; u < 8; ++u) mm[u] = s_metaS[start + j + u];
        const float4* vr[8];
        float4 ef[8];
        #pragma unroll
        for (int u = 0; u < 8; ++u) {
            vr[u] = (const float4*)(v + (size_t)(mm[u] >> 12) * 16);
            ef[u] = s_efA[mm[u] & 4095u];
        }
        // two passes of 4 edges; all 8 load streams independent
        #pragma unroll
        for (int u = 0; u < 8; ++u) {
            float4 a0 = vr[u][0], a1 = vr[u][1], a2 = vr[u][2], a3 = vr[u][3];
            EDGE_FMA(ef[u], a0, a1, a2, a3)
        }
    }
    for (; j + 4 <= deg; j += 4) {
        unsigned mm[4];
        #pragma unroll
        for (int u = 0; u < 4; ++u) mm[u] = s_metaS[start + j + u];
        #pragma unroll
        for (int u = 0; u < 4; ++u) {
            const float4* vru = (const float4*)(v + (size_t)(mm[u] >> 12) * 16);
            float4 efu = s_efA[mm[u] & 4095u];
            float4 a0 = vru[0], a1 = vru[1], a2 = vru[2], a3 = vru[3];
            EDGE_FMA(efu, a0, a1, a2, a3)
        }
    }
    for (; j < deg; ++j) {
        unsigned m0 = s_metaS[start + j];
        const float4* vru = (const float4*)(v + (size_t)(m0 >> 12) * 16);
        float4 efu = s_efA[m0 & 4095u];
        float4 a0 = vru[0], a1 = vru[1], a2 = vru[2], a3 = vru[3];
        EDGE_FMA(efu, a0, a1, a2, a3)
    }

    float val[16];
    if (active) {
        float vn[16];
        #pragma unroll
        for (int i = 0; i < 4; ++i) {
            float4 tv = *(const float4*)(v + (size_t)n * 16 + i * 4);
            vn[4*i+0] = tv.x; vn[4*i+1] = tv.y;
            vn[4*i+2] = tv.z; vn[4*i+3] = tv.w;
        }
        float scale = 1.0f / fmaxf((float)deg, 1.0f);
        #pragma unroll
        for (int o = 0; o < 16; ++o) {
            float a = 0.0f;
            #pragma unroll
            for (int i = 0; i < 16; ++i) {
                a = fmaf(acc[i], enet_b[i * 16 + o], a);           // S0 * B
                #pragma unroll
                for (int k = 0; k < 4; ++k)
                    a = fmaf(acc[16 + k * 16 + i],
                             enet_w[(i * 16 + o) * 4 + k], a);     // Sk * Wk
            }
            a = fmaf(a, scale, bias[o]);
            #pragma unroll
            for (int i = 0; i < 16; ++i)
                a = fmaf(vn[i], root[i * 16 + o], a);
            val[o] = a;
        }
        #pragma unroll
        for (int i = 0; i < 4; ++i)
            *(float4*)(out + (size_t)n * 16 + i * 4) =
                make_float4(val[4*i+0], val[4*i+1], val[4*i+2], val[4*i+3]);
    } else {
        #pragma unroll
        for (int o = 0; o < 16; ++o) val[o] = 0.0f;
    }

    // batch-stat reduction: wave butterfly -> LDS -> device atomic
    float ssum[16], ssq[16];
    #pragma unroll
    for (int o = 0; o < 16; ++o) {
        float a = val[o];
        float bsq = a * a;
        #pragma unroll
        for (int m = 1; m < 64; m <<= 1) {
            a += __shfl_xor(a, m, 64);
            bsq += __shfl_xor(bsq, m, 64);
        }
        ssum[o] = a; ssq[o] = bsq;
    }
    int wave = tid >> 6;
    int lane = tid & 63;
    if (lane == 0) {
        #pragma unroll
        for (int o = 0; o < 16; ++o) {
            s_part[wave][o]      = ssum[o];
            s_part[wave][16 + o] = ssq[o];
        }
    }
    __syncthreads();
    if (tid < 32) {
        float t = s_part[0][tid] + s_part[1][tid] +
                  s_part[2][tid] + s_part[3][tid];
        unsafeAtomicAdd(stats + tid, t);
    }
}

// Kernel 3: BatchNorm (batch stats) + LeakyReLU, in place. (unchanged)
__global__ __launch_bounds__(256) void final_kernel(
    float* __restrict__ out,
    const float* __restrict__ stats,
    const float* __restrict__ gamma,
    const float* __restrict__ beta)
{
    int idx = blockIdx.x * 256 + threadIdx.x;      // float4 index
    if (idx >= N_NODES * 4) return;
    int o0 = (idx & 3) << 2;
    const float invN = 1.0f / (float)N_NODES;
    float4 x = *((const float4*)out + idx);
    float xs[4] = {x.x, x.y, x.z, x.w};
    float r[4];
    #pragma unroll
    for (int u = 0; u < 4; ++u) {
        int o = o0 + u;
        float mu = stats[o] * invN;
        float var = fmaxf(stats[16 + o] * invN - mu * mu, 0.0f);
        float y = fmaf(gamma[o] * (xs[u] - mu), rsqrtf(var + EPS), beta[o]);
        r[u] = (y >= 0.0f) ? y : SLOPE * y;
    }
    *((float4*)out + idx) = make_float4(r[0], r[1], r[2], r[3]);
}

extern "C" void kernel_launch(void* const* d_in, const int* in_sizes, int n_in,
                              void* d_out, int out_size, void* d_ws, size_t ws_size,
                              hipStream_t stream)
{
    const float* v = (const float*)d_in[0];
    const float* e = (const float*)d_in[1];
    const int* edge_index = (const int*)d_in[2];
    const float* enet_w = (const float*)d_in[3];
    const float* enet_b = (const float*)d_in[4];
    const float* root = (const float*)d_in[5];
    const float* bias = (const float*)d_in[6];
    const float* gamma = (const float*)d_in[7];
    const float* beta = (const float*)d_in[8];
    float* out = (float*)d_out;

    char* ws = (char*)d_ws;
    float4*       pef   = (float4*)ws;    ws += (size_t)NBUCK * KSUB * SCAP * 16;
    unsigned int* meta  = (unsigned int*)ws;
                                          ws += (size_t)NBUCK * KSUB * SCAP * 4;
    int*          bcur  = (int*)ws;       ws += (size_t)NBUCK * KSUB * 4;
    float*        stats = (float*)ws;

    // zero bcur + stats (contiguous, tiny)
    hipMemsetAsync(bcur, 0, (size_t)NBUCK * KSUB * 4 + 32 * 4, stream);

    bin_kernel<<<NBINB, 256, 0, stream>>>(e, edge_index, bcur, pef, meta);
    gather_bucket_kernel<<<NBUCK, 256, 0, stream>>>(
        v, pef, meta, bcur, enet_w, enet_b, root, bias, out, stats);
    final_kernel<<<(N_NODES * 4 + 255) / 256, 256, 0, stream>>>(
        out, stats, gamma, beta);
}

// Round 21
// 169.992 us; speedup vs baseline: 1.1146x; 1.1146x over previous
//
#include <hip/hip_runtime.h>

#define N_NODES 100000
#define N_EDGES 1000000
#define EPS 1e-5f
#define SLOPE 0.01f
#define NBUCK 391    // ceil(N/256) buckets of 256 consecutive nodes
#define EPB 2560     // edges per bin block
#define NBINB 391    // bin blocks
#define KSUB 8       // sub-cursors per bucket (blockIdx % 8)
#define SCAP 480     // records per (bucket, sub): mean 320 + 8.9 sigma
#define CCAP 3072    // records per bucket in gather LDS (2560 + 10 sigma)

// ---------------------------------------------------------------------------
// ws layout:
//   pef  : NBUCK*KSUB*SCAP*16 B (24.0 MB) edge features, (bucket, sub)-major
//   meta : NBUCK*KSUB*SCAP*4 B  (6.0 MB)  (src<<8 | dst&255) per record
//   bcur : NBUCK*KSUB ints [zeroed]       sub-cursors
//   stats: 32 floats [zeroed]             sum[16], sumsq[16]
// Measured design rules:
//   r5/r6/r16: 1 thread/node is the right gather shape (all lane-splits lose).
//   r8/r9 : grid.sync fusion is NOT coherence-safe on 8-XCD MI355X.
//   r10   : nt stores/L2-bypass regress; plain cached stores optimal.
//   r12-15: same-address atomic RMW = 137 ns; 8-way sub-cursors @391 blocks.
//   r17-19: 20 B/edge bin format + ef staged in LDS; gather FETCH at floor.
//   r20   : x8 "unroll" serialized the streams (one edge's loads consumed at
//           a time) AND LDS 80.4 KB sat at the 2-blocks/CU cliff -> occ 8%.
//   r21   : CSR-order LDS payload via two-pass meta read: deletes metaA/dl/
//           metaS (LDS 80.4 -> 63.5 KB, 2 blk/CU restored), phase D LDS
//           reads fully CONTIGUOUS (no pos indirection, no conflicts).
// ---------------------------------------------------------------------------

// Kernel 1: bin edges into (bucket, sub)-major staging. (r17-r19, unchanged)
__global__ __launch_bounds__(256) void bin_kernel(
    const float* __restrict__ efeat,
    const int* __restrict__ edge_index,
    int* __restrict__ bcur,
    float4* __restrict__ pef,
    unsigned int* __restrict__ meta)
{
    __shared__ int s_hist[NBUCK];
    __shared__ int s_base[NBUCK];

    const int tid = threadIdx.x;
    const int ksub = blockIdx.x & (KSUB - 1);
    const int e0 = blockIdx.x * EPB;
    const int e1 = min(e0 + EPB, N_EDGES);

    for (int i = tid; i < NBUCK; i += 256) s_hist[i] = 0;
    __syncthreads();
    for (int eid = e0 + tid; eid < e1; eid += 256) {
        int dst = edge_index[N_EDGES + eid];
        atomicAdd(&s_hist[dst >> 8], 1);
    }
    __syncthreads();

    for (int b = tid; b < NBUCK; b += 256) {
        int c = s_hist[b];
        s_base[b] = c ? atomicAdd(bcur + b * KSUB + ksub, c) : 0;
    }
    __syncthreads();
    for (int i = tid; i < NBUCK; i += 256) s_hist[i] = 0;   // reuse as cursor
    __syncthreads();

    for (int eid = e0 + tid; eid < e1; eid += 256) {
        int src = edge_index[eid];
        int dst = edge_index[N_EDGES + eid];
        float4 ef = *(const float4*)(efeat + (size_t)eid * 4);
        int b = dst >> 8;
        int slot = s_base[b] + atomicAdd(&s_hist[b], 1);
        if (slot < SCAP) {                      // 8.9-sigma margin; never trips
            size_t rec = ((size_t)b * KSUB + ksub) * SCAP + slot;
            pef[rec]  = ef;
            meta[rec] = ((unsigned)src << 8) | (unsigned)(dst & 255);
        }
    }
}

// ---------------------------------------------------------------------------
// Kernel 2: per-bucket fused CSR-build + gather + node transform.
// Two-pass phase A: (1) histogram from meta; scan; (2) re-read meta (L2-hot)
// + pef, scatter {src, ef} DIRECTLY into CSR order in LDS. Phase D reads
// s_srcS / s_efS contiguously -> conflict-free front-end, one global round.
// LDS 63.5 KB -> 2 blocks/CU resident.
// ---------------------------------------------------------------------------
__global__ __launch_bounds__(256) void gather_bucket_kernel(
    const float* __restrict__ v,
    const float4* __restrict__ pef,
    const unsigned int* __restrict__ meta,
    const int* __restrict__ bcur,
    const float* __restrict__ enet_w,
    const float* __restrict__ enet_b,
    const float* __restrict__ root,
    const float* __restrict__ bias,
    float* __restrict__ out,
    float* __restrict__ stats)
{
    __shared__ float4 s_efS[CCAP];            // 48 KB  ef, CSR order
    __shared__ int s_srcS[CCAP];              // 12 KB  src, CSR order
    __shared__ int s_hist[256];
    __shared__ int s_sc[256];
    __shared__ int s_cur[256];
    __shared__ float s_part[4][32];

    const int b = blockIdx.x;
    const int tid = threadIdx.x;

    // A1) segment counts (uniform) + histogram from meta
    int ck[KSUB];
    int cnt = 0;
    #pragma unroll
    for (int k = 0; k < KSUB; ++k) {
        int c = min(bcur[b * KSUB + k], SCAP);
        if (cnt + c > CCAP) c = CCAP - cnt;   // theoretical guard
        ck[k] = c;
        cnt += c;
    }
    s_hist[tid] = 0;
    __syncthreads();
    #pragma unroll
    for (int k = 0; k < KSUB; ++k) {
        size_t segbase = ((size_t)b * KSUB + k) * SCAP;
        for (int i = tid; i < ck[k]; i += 256)
            atomicAdd(&s_hist[meta[segbase + i] & 255u], 1);
    }
    __syncthreads();

    // B) exclusive scan of s_hist
    int deg = s_hist[tid];
    s_sc[tid] = deg;
    __syncthreads();
    #pragma unroll
    for (int offs = 1; offs < 256; offs <<= 1) {
        int t = (tid >= offs) ? s_sc[tid - offs] : 0;
        __syncthreads();
        s_sc[tid] += t;
        __syncthreads();
    }
    int start = s_sc[tid] - deg;
    s_cur[tid] = start;
    __syncthreads();

    // A2/C) re-read meta (L2-hot) + pef; scatter {src, ef} into CSR order
    #pragma unroll
    for (int k = 0; k < KSUB; ++k) {
        size_t segbase = ((size_t)b * KSUB + k) * SCAP;
        for (int i = tid; i < ck[k]; i += 256) {
            unsigned m = meta[segbase + i];
            float4 ef = pef[segbase + i];
            int slot = atomicAdd(&s_cur[m & 255u], 1);
            s_srcS[slot] = (int)(m >> 8);
            s_efS[slot] = ef;
        }
    }
    __syncthreads();

    // D) gather, x4 ILP unroll (r19 interleaved-stream body). Front-end per
    //    chunk: contiguous s_srcS + s_efS reads -> 4 independent v-globals.
    int n = b * 256 + tid;
    bool active = (n < N_NODES);

    float acc[80];
    #pragma unroll
    for (int i = 0; i < 80; ++i) acc[i] = 0.0f;

    int j = 0;
    for (; j + 4 <= deg; j += 4) {
        int s0 = s_srcS[start + j + 0];
        int s1 = s_srcS[start + j + 1];
        int s2 = s_srcS[start + j + 2];
        int s3 = s_srcS[start + j + 3];
        float4 ef0 = s_efS[start + j + 0];
        float4 ef1 = s_efS[start + j + 1];
        float4 ef2 = s_efS[start + j + 2];
        float4 ef3 = s_efS[start + j + 3];
        const float4* vr0 = (const float4*)(v + (size_t)s0 * 16);
        const float4* vr1 = (const float4*)(v + (size_t)s1 * 16);
        const float4* vr2 = (const float4*)(v + (size_t)s2 * 16);
        const float4* vr3 = (const float4*)(v + (size_t)s3 * 16);
        #pragma unroll
        for (int i = 0; i < 4; ++i) {
            float4 a = vr0[i], bb = vr1[i], c = vr2[i], d = vr3[i];
            acc[     i*4+0] += (a.x + bb.x) + (c.x + d.x);
            acc[     i*4+1] += (a.y + bb.y) + (c.y + d.y);
            acc[     i*4+2] += (a.z + bb.z) + (c.z + d.z);
            acc[     i*4+3] += (a.w + bb.w) + (c.w + d.w);
            acc[16 + i*4+0] = fmaf(ef0.x, a.x, fmaf(ef1.x, bb.x,
                              fmaf(ef2.x, c.x, fmaf(ef3.x, d.x, acc[16 + i*4+0]))));
            acc[16 + i*4+1] = fmaf(ef0.x, a.y, fmaf(ef1.x, bb.y,
                              fmaf(ef2.x, c.y, fmaf(ef3.x, d.y, acc[16 + i*4+1]))));
            acc[16 + i*4+2] = fmaf(ef0.x, a.z, fmaf(ef1.x, bb.z,
                              fmaf(ef2.x, c.z, fmaf(ef3.x, d.z, acc[16 + i*4+2]))));
            acc[16 + i*4+3] = fmaf(ef0.x, a.w, fmaf(ef1.x, bb.w,
                              fmaf(ef2.x, c.w, fmaf(ef3.x, d.w, acc[16 + i*4+3]))));
            acc[32 + i*4+0] = fmaf(ef0.y, a.x, fmaf(ef1.y, bb.x,
                              fmaf(ef2.y, c.x, fmaf(ef3.y, d.x, acc[32 + i*4+0]))));
            acc[32 + i*4+1] = fmaf(ef0.y, a.y, fmaf(ef1.y, bb.y,
                              fmaf(ef2.y, c.y, fmaf(ef3.y, d.y, acc[32 + i*4+1]))));
            acc[32 + i*4+2] = fmaf(ef0.y, a.z, fmaf(ef1.y, bb.z,
                              fmaf(ef2.y, c.z, fmaf(ef3.y, d.z, acc[32 + i*4+2]))));
            acc[32 + i*4+3] = fmaf(ef0.y, a.w, fmaf(ef1.y, bb.w,
                              fmaf(ef2.y, c.w, fmaf(ef3.y, d.w, acc[32 + i*4+3]))));
            acc[48 + i*4+0] = fmaf(ef0.z, a.x, fmaf(ef1.z, bb.x,
                              fmaf(ef2.z, c.x, fmaf(ef3.z, d.x, acc[48 + i*4+0]))));
            acc[48 + i*4+1] = fmaf(ef0.z, a.y, fmaf(ef1.z, bb.y,
                              fmaf(ef2.z, c.y, fmaf(ef3.z, d.y, acc[48 + i*4+1]))));
            acc[48 + i*4+2] = fmaf(ef0.z, a.z, fmaf(ef1.z, bb.z,
                              fmaf(ef2.z, c.z, fmaf(ef3.z, d.z, acc[48 + i*4+2]))));
            acc[48 + i*4+3] = fmaf(ef0.z, a.w, fmaf(ef1.z, bb.w,
                              fmaf(ef2.z, c.w, fmaf(ef3.z, d.w, acc[48 + i*4+3]))));
            acc[64 + i*4+0] = fmaf(ef0.w, a.x, fmaf(ef1.w, bb.x,
                              fmaf(ef2.w, c.x, fmaf(ef3.w, d.x, acc[64 + i*4+0]))));
            acc[64 + i*4+1] = fmaf(ef0.w, a.y, fmaf(ef1.w, bb.y,
                              fmaf(ef2.w, c.y, fmaf(ef3.w, d.y, acc[64 + i*4+1]))));
            acc[64 + i*4+2] = fmaf(ef0.w, a.z, fmaf(ef1.w, bb.z,
                              fmaf(ef2.w, c.z, fmaf(ef3.w, d.z, acc[64 + i*4+2]))));
            acc[64 + i*4+3] = fmaf(ef0.w, a.w, fmaf(ef1.w, bb.w,
                              fmaf(ef2.w, c.w, fmaf(ef3.w, d.w, acc[64 + i*4+3]))));
        }
    }
    for (; j < deg; ++j) {
        int s0 = s_srcS[start + j];
        float4 ef = s_efS[start + j];
        const float4* vr = (const float4*)(v + (size_t)s0 * 16);
        #pragma unroll
        for (int i = 0; i < 4; ++i) {
            float4 a = vr[i];
            acc[     i*4+0] += a.x;
            acc[     i*4+1] += a.y;
            acc[     i*4+2] += a.z;
            acc[     i*4+3] += a.w;
            acc[16 + i*4+0] = fmaf(ef.x, a.x, acc[16 + i*4+0]);
            acc[16 + i*4+1] = fmaf(ef.x, a.y, acc[16 + i*4+1]);
            acc[16 + i*4+2] = fmaf(ef.x, a.z, acc[16 + i*4+2]);
            acc[16 + i*4+3] = fmaf(ef.x, a.w, acc[16 + i*4+3]);
            acc[32 + i*4+0] = fmaf(ef.y, a.x, acc[32 + i*4+0]);
            acc[32 + i*4+1] = fmaf(ef.y, a.y, acc[32 + i*4+1]);
            acc[32 + i*4+2] = fmaf(ef.y, a.z, acc[32 + i*4+2]);
            acc[32 + i*4+3] = fmaf(ef.y, a.w, acc[32 + i*4+3]);
            acc[48 + i*4+0] = fmaf(ef.z, a.x, acc[48 + i*4+0]);
            acc[48 + i*4+1] = fmaf(ef.z, a.y, acc[48 + i*4+1]);
            acc[48 + i*4+2] = fmaf(ef.z, a.z, acc[48 + i*4+2]);
            acc[48 + i*4+3] = fmaf(ef.z, a.w, acc[48 + i*4+3]);
            acc[64 + i*4+0] = fmaf(ef.w, a.x, acc[64 + i*4+0]);
            acc[64 + i*4+1] = fmaf(ef.w, a.y, acc[64 + i*4+1]);
            acc[64 + i*4+2] = fmaf(ef.w, a.z, acc[64 + i*4+2]);
            acc[64 + i*4+3] = fmaf(ef.w, a.w, acc[64 + i*4+3]);
        }
    }

    float val[16];
    if (active) {
        float vn[16];
        #pragma unroll
        for (int i = 0; i < 4; ++i) {
            float4 tv = *(const float4*)(v + (size_t)n * 16 + i * 4);
            vn[4*i+0] = tv.x; vn[4*i+1] = tv.y;
            vn[4*i+2] = tv.z; vn[4*i+3] = tv.w;
        }
        float scale = 1.0f / fmaxf((float)deg, 1.0f);
        #pragma unroll
        for (int o = 0; o < 16; ++o) {
            float a = 0.0f;
            #pragma unroll
            for (int i = 0; i < 16; ++i) {
                a = fmaf(acc[i], enet_b[i * 16 + o], a);           // S0 * B
                #pragma unroll
                for (int k = 0; k < 4; ++k)
                    a = fmaf(acc[16 + k * 16 + i],
                             enet_w[(i * 16 + o) * 4 + k], a);     // Sk * Wk
            }
            a = fmaf(a, scale, bias[o]);
            #pragma unroll
            for (int i = 0; i < 16; ++i)
                a = fmaf(vn[i], root[i * 16 + o], a);
            val[o] = a;
        }
        #pragma unroll
        for (int i = 0; i < 4; ++i)
            *(float4*)(out + (size_t)n * 16 + i * 4) =
                make_float4(val[4*i+0], val[4*i+1], val[4*i+2], val[4*i+3]);
    } else {
        #pragma unroll
        for (int o = 0; o < 16; ++o) val[o] = 0.0f;
    }

    // batch-stat reduction: wave butterfly -> LDS -> device atomic
    float ssum[16], ssq[16];
    #pragma unroll
    for (int o = 0; o < 16; ++o) {
        float a = val[o];
        float bsq = a * a;
        #pragma unroll
        for (int m = 1; m < 64; m <<= 1) {
            a += __shfl_xor(a, m, 64);
            bsq += __shfl_xor(bsq, m, 64);
        }
        ssum[o] = a; ssq[o] = bsq;
    }
    int wave = tid >> 6;
    int lane = tid & 63;
    if (lane == 0) {
        #pragma unroll
        for (int o = 0; o < 16; ++o) {
            s_part[wave][o]      = ssum[o];
            s_part[wave][16 + o] = ssq[o];
        }
    }
    __syncthreads();
    if (tid < 32) {
        float t = s_part[0][tid] + s_part[1][tid] +
                  s_part[2][tid] + s_part[3][tid];
        unsafeAtomicAdd(stats + tid, t);
    }
}

// Kernel 3: BatchNorm (batch stats) + LeakyReLU, in place. (unchanged)
__global__ __launch_bounds__(256) void final_kernel(
    float* __restrict__ out,
    const float* __restrict__ stats,
    const float* __restrict__ gamma,
    const float* __restrict__ beta)
{
    int idx = blockIdx.x * 256 + threadIdx.x;      // float4 index
    if (idx >= N_NODES * 4) return;
    int o0 = (idx & 3) << 2;
    const float invN = 1.0f / (float)N_NODES;
    float4 x = *((const float4*)out + idx);
    float xs[4] = {x.x, x.y, x.z, x.w};
    float r[4];
    #pragma unroll
    for (int u = 0; u < 4; ++u) {
        int o = o0 + u;
        float mu = stats[o] * invN;
        float var = fmaxf(stats[16 + o] * invN - mu * mu, 0.0f);
        float y = fmaf(gamma[o] * (xs[u] - mu), rsqrtf(var + EPS), beta[o]);
        r[u] = (y >= 0.0f) ? y : SLOPE * y;
    }
    *((float4*)out + idx) = make_float4(r[0], r[1], r[2], r[3]);
}

extern "C" void kernel_launch(void* const* d_in, const int* in_sizes, int n_in,
                              void* d_out, int out_size, void* d_ws, size_t ws_size,
                              hipStream_t stream)
{
    const float* v = (const float*)d_in[0];
    const float* e = (const float*)d_in[1];
    const int* edge_index = (const int*)d_in[2];
    const float* enet_w = (const float*)d_in[3];
    const float* enet_b = (const float*)d_in[4];
    const float* root = (const float*)d_in[5];
    const float* bias = (const float*)d_in[6];
    const float* gamma = (const float*)d_in[7];
    const float* beta = (const float*)d_in[8];
    float* out = (float*)d_out;

    char* ws = (char*)d_ws;
    float4*       pef   = (float4*)ws;    ws += (size_t)NBUCK * KSUB * SCAP * 16;
    unsigned int* meta  = (unsigned int*)ws;
                                          ws += (size_t)NBUCK * KSUB * SCAP * 4;
    int*          bcur  = (int*)ws;       ws += (size_t)NBUCK * KSUB * 4;
    float*        stats = (float*)ws;

    // zero bcur + stats (contiguous, tiny)
    hipMemsetAsync(bcur, 0, (size_t)NBUCK * KSUB * 4 + 32 * 4, stream);

    bin_kernel<<<NBINB, 256, 0, stream>>>(e, edge_index, bcur, pef, meta);
    gather_bucket_kernel<<<NBUCK, 256, 0, stream>>>(
        v, pef, meta, bcur, enet_w, enet_b, root, bias, out, stats);
    final_kernel<<<(N_NODES * 4 + 255) / 256, 256, 0, stream>>>(
        out, stats, gamma, beta);
}